// Round 1
// baseline (337.931 us; speedup 1.0000x reference)
//
#include <hip/hip_runtime.h>
#include <hip/hip_bf16.h>

typedef unsigned short u16;
typedef __bf16 bfx8 __attribute__((ext_vector_type(8)));
typedef float fx4 __attribute__((ext_vector_type(4)));

#define DEV __device__ __forceinline__

static constexpr int Lq = 2048, Dq = 768, DIN = 1536, NST = 16;
static constexpr int NCH = 32, LC = 64;   // scan chunks: 32 x 64 = 2048

DEV u16 f2bf(float x) {
    union { float f; unsigned u; } v; v.f = x;
    unsigned r = v.u + 0x7fff + ((v.u >> 16) & 1);
    return (u16)(r >> 16);
}

// ---------------- transpose + cast f32 -> bf16, with zero padding ----------------
// src: R x C (f32, row-major). dst: Cp x Rp (bf16, row-major), dst[c][r] = src[r][c], 0 outside.
__global__ __launch_bounds__(256) void transpose_cast(const float* __restrict__ src, int R, int C,
                                                      u16* __restrict__ dst, int Rp, int Cp) {
    __shared__ float tile[32][33];
    int c0 = blockIdx.x * 32, r0 = blockIdx.y * 32;
    int tx = threadIdx.x & 31, ty = threadIdx.x >> 5;   // 32 x 8
    #pragma unroll
    for (int i = ty; i < 32; i += 8) {
        int r = r0 + i, c = c0 + tx;
        tile[i][tx] = (r < R && c < C) ? src[(size_t)r * C + c] : 0.f;
    }
    __syncthreads();
    #pragma unroll
    for (int i = ty; i < 32; i += 8) {
        int c = c0 + i, r = r0 + tx;
        if (c < Cp && r < Rp) dst[(size_t)c * Rp + r] = f2bf(tile[tx][i]);
    }
}

// ---------------- RMSNorm -> bf16 ----------------
__global__ __launch_bounds__(256) void rmsnorm_kernel(const float* __restrict__ x,
                                                      const float* __restrict__ w,
                                                      u16* __restrict__ xn) {
    int t = blockIdx.x;
    const float* row = x + (size_t)t * Dq;
    float ss = 0.f;
    for (int i = threadIdx.x; i < Dq; i += 256) { float a = row[i]; ss += a * a; }
    #pragma unroll
    for (int o = 32; o > 0; o >>= 1) ss += __shfl_xor(ss, o, 64);
    __shared__ float wsum[4];
    if ((threadIdx.x & 63) == 0) wsum[threadIdx.x >> 6] = ss;
    __syncthreads();
    ss = wsum[0] + wsum[1] + wsum[2] + wsum[3];
    float scale = rsqrtf(ss * (1.f / Dq) + 1e-5f);
    for (int i = threadIdx.x; i < Dq; i += 256)
        xn[(size_t)t * Dq + i] = f2bf(row[i] * scale * w[i]);
}

// ---------------- generic NT bf16 MFMA GEMM ----------------
// A: M x K bf16 row-major. BT: N x K bf16 row-major. C: M x N f32.
// EPI 0: C = acc (+R if R). EPI 1: C = softplus(acc + bias[col]). EPI 2: atomicAdd(C, acc).
template<int BM, int BN, int EPI>
__global__ __launch_bounds__(256) void gemm_nt(const u16* __restrict__ A, const u16* __restrict__ BT,
                                               float* __restrict__ C, const float* __restrict__ R,
                                               const float* __restrict__ bias,
                                               int M, int N, int K, int kLen) {
    constexpr int BK = 32, LDT = 40;       // +8 bf16 pad: 80B row stride, conflict-benign
    constexpr int WM = BM / 2, WN = BN / 2, MI = WM / 16, NI = WN / 16;
    __shared__ u16 As[BM * LDT];
    __shared__ u16 Bs[BN * LDT];
    const int tid = threadIdx.x, lane = tid & 63, wid = tid >> 6;
    const int wr = wid >> 1, wc = wid & 1;
    const int bm0 = blockIdx.y * BM, bn0 = blockIdx.x * BN;
    const int k0 = blockIdx.z * kLen;
    const int li = lane & 15, g = lane >> 4;

    fx4 acc[MI][NI];
    #pragma unroll
    for (int mi = 0; mi < MI; mi++)
        #pragma unroll
        for (int ni = 0; ni < NI; ni++)
            #pragma unroll
            for (int q = 0; q < 4; q++) acc[mi][ni][q] = 0.f;

    for (int kt = k0; kt < k0 + kLen; kt += BK) {
        #pragma unroll
        for (int i = 0; i < (BM * 4) / 256; i++) {
            int ch = tid + i * 256; int r = ch >> 2, kc = (ch & 3) * 8;
            *(float4*)(&As[r * LDT + kc]) = *(const float4*)(A + (size_t)(bm0 + r) * K + kt + kc);
        }
        #pragma unroll
        for (int i = 0; i < (BN * 4) / 256; i++) {
            int ch = tid + i * 256; int r = ch >> 2, kc = (ch & 3) * 8;
            *(float4*)(&Bs[r * LDT + kc]) = *(const float4*)(BT + (size_t)(bn0 + r) * K + kt + kc);
        }
        __syncthreads();
        bfx8 af[MI], bfr[NI];
        #pragma unroll
        for (int mi = 0; mi < MI; mi++) af[mi] = *(const bfx8*)&As[(wr * WM + mi * 16 + li) * LDT + g * 8];
        #pragma unroll
        for (int ni = 0; ni < NI; ni++) bfr[ni] = *(const bfx8*)&Bs[(wc * WN + ni * 16 + li) * LDT + g * 8];
        #pragma unroll
        for (int mi = 0; mi < MI; mi++)
            #pragma unroll
            for (int ni = 0; ni < NI; ni++)
                acc[mi][ni] = __builtin_amdgcn_mfma_f32_16x16x32_bf16(af[mi], bfr[ni], acc[mi][ni], 0, 0, 0);
        __syncthreads();
    }

    #pragma unroll
    for (int mi = 0; mi < MI; mi++)
        #pragma unroll
        for (int ni = 0; ni < NI; ni++)
            #pragma unroll
            for (int q = 0; q < 4; q++) {
                int row = bm0 + wr * WM + mi * 16 + g * 4 + q;
                int col = bn0 + wc * WN + ni * 16 + li;
                size_t idx = (size_t)row * N + col;
                float v = acc[mi][ni][q];
                if constexpr (EPI == 0) {
                    if (R) v += R[idx];
                    C[idx] = v;
                } else if constexpr (EPI == 1) {
                    v += bias[col];
                    C[idx] = (v > 20.f) ? v : log1pf(__expf(v));
                } else {
                    atomicAdd(&C[idx], v);
                }
            }
}

// ---------------- depthwise causal conv (K=4) + bias + SiLU ----------------
__global__ __launch_bounds__(256) void conv_silu(const float* __restrict__ xr,
                                                 const float* __restrict__ cw,
                                                 const float* __restrict__ cb,
                                                 float* __restrict__ u, u16* __restrict__ ubf) {
    int i = blockIdx.x * 256 + threadIdx.x;
    if (i >= Lq * DIN) return;
    int t = i / DIN, d = i - t * DIN;
    float acc = cb[d];
    #pragma unroll
    for (int k = 0; k < 4; k++) {
        int tt = t - 3 + k;
        if (tt >= 0) acc += xr[(size_t)tt * (2 * DIN) + d] * cw[k * DIN + d];
    }
    float s = acc / (1.f + __expf(-acc));
    u[i] = s;
    ubf[i] = f2bf(s);
}

// ---------------- cast delta_raw (cols 0..63 of padded x_dbl) to bf16 ----------------
__global__ __launch_bounds__(256) void cast_draw(const float* __restrict__ xdbl, u16* __restrict__ draw) {
    int i = blockIdx.x * 256 + threadIdx.x;
    if (i >= Lq * 64) return;
    int t = i >> 6, k = i & 63;
    draw[i] = f2bf(xdbl[(size_t)t * 128 + k]);
}

// ---------------- selective scan, 3-pass chunked ----------------
// pass 1: per (chunk, d, n): local scan from 0; store chunk A-product and end-state.
__global__ __launch_bounds__(256) void scan_p1(const float* __restrict__ delta, const float* __restrict__ u,
                                               const float* __restrict__ xdbl, const float* __restrict__ A_log,
                                               float* __restrict__ chA, float* __restrict__ chX) {
    int c = blockIdx.x, dblk = blockIdx.y;
    int n = threadIdx.x & 15, dloc = threadIdx.x >> 4;
    int d = dblk * 16 + dloc;
    float An = -__expf(A_log[d * NST + n]);
    float s = 0.f, ap = 1.f;
    int t0 = c * LC;
    for (int t = t0; t < t0 + LC; t++) {
        float dl = delta[(size_t)t * DIN + d];
        float uu = u[(size_t)t * DIN + d];
        float Bn = xdbl[(size_t)t * 128 + 48 + n];
        float dA = __expf(dl * An);
        s = dA * s + dl * Bn * uu;
        ap *= dA;
    }
    size_t idx = ((size_t)c * DIN + d) * NST + n;
    chA[idx] = ap; chX[idx] = s;
}

// pass 2: sequential combine over chunks -> initial state per chunk.
__global__ __launch_bounds__(256) void scan_p2(const float* __restrict__ chA, const float* __restrict__ chX,
                                               float* __restrict__ init) {
    int i = blockIdx.x * 256 + threadIdx.x;   // i = d*16+n
    float s = 0.f;
    for (int c = 0; c < NCH; c++) {
        size_t idx = (size_t)c * (DIN * NST) + i;
        init[idx] = s;
        s = chA[idx] * s + chX[idx];
    }
}

// pass 3: rescan with init, reduce over n, gate, -> y bf16.
__global__ __launch_bounds__(256) void scan_p3(const float* __restrict__ delta, const float* __restrict__ u,
                                               const float* __restrict__ xdbl, const float* __restrict__ A_log,
                                               const float* __restrict__ init, const float* __restrict__ Dp,
                                               const float* __restrict__ xr, u16* __restrict__ ybf) {
    int c = blockIdx.x, dblk = blockIdx.y;
    int n = threadIdx.x & 15, dloc = threadIdx.x >> 4;
    int d = dblk * 16 + dloc;
    float An = -__expf(A_log[d * NST + n]);
    float s = init[(size_t)c * (DIN * NST) + d * NST + n];
    float Dpd = Dp[d];
    int t0 = c * LC;
    for (int t = t0; t < t0 + LC; t++) {
        float dl = delta[(size_t)t * DIN + d];
        float uu = u[(size_t)t * DIN + d];
        float Bn = xdbl[(size_t)t * 128 + 48 + n];
        float Cn = xdbl[(size_t)t * 128 + 64 + n];
        float dA = __expf(dl * An);
        s = dA * s + dl * Bn * uu;
        float p = s * Cn;
        p += __shfl_xor(p, 1, 16);
        p += __shfl_xor(p, 2, 16);
        p += __shfl_xor(p, 4, 16);
        p += __shfl_xor(p, 8, 16);
        if (n == 0) {
            float res = xr[(size_t)t * (2 * DIN) + DIN + d];
            float y = (p + uu * Dpd) * (res / (1.f + __expf(-res)));
            ybf[(size_t)t * DIN + d] = f2bf(y);
        }
    }
}

extern "C" void kernel_launch(void* const* d_in, const int* in_sizes, int n_in,
                              void* d_out, int out_size, void* d_ws, size_t ws_size,
                              hipStream_t stream) {
    const float* x      = (const float*)d_in[0];
    const float* norm_w = (const float*)d_in[1];
    const float* W_in   = (const float*)d_in[2];
    const float* conv_w = (const float*)d_in[3];
    const float* conv_b = (const float*)d_in[4];
    const float* W_x    = (const float*)d_in[5];
    const float* W_dt   = (const float*)d_in[6];
    const float* b_dt   = (const float*)d_in[7];
    const float* A_log  = (const float*)d_in[8];
    const float* Dp     = (const float*)d_in[9];
    const float* W_out  = (const float*)d_in[10];
    float* out = (float*)d_out;

    char* wp = (char*)d_ws;
    auto alloc = [&](size_t bytes) { char* p = wp; wp += (bytes + 255) & ~(size_t)255; return p; };
    u16*   WinT  = (u16*)alloc((size_t)3072 * 768 * 2);    // W_in^T  (3072 x 768)
    u16*   WoutT = (u16*)alloc((size_t)768 * 1536 * 2);    // W_out^T (768 x 1536)
    u16*   WxT   = (u16*)alloc((size_t)128 * 1536 * 2);    // W_x^T padded (128 x 1536)
    u16*   WdtT  = (u16*)alloc((size_t)1536 * 64 * 2);     // W_dt^T padded (1536 x 64)
    u16*   xn    = (u16*)alloc((size_t)Lq * Dq * 2);       // rmsnorm(x) bf16
    float* xr    = (float*)alloc((size_t)Lq * 3072 * 4);   // x @ W_in
    float* u     = (float*)alloc((size_t)Lq * DIN * 4);    // silu(conv)
    u16*   ubf   = (u16*)alloc((size_t)Lq * DIN * 2);
    float* xdbl  = (float*)alloc((size_t)Lq * 128 * 4);    // u @ W_x (padded to 128 cols)
    u16*   draw  = (u16*)alloc((size_t)Lq * 64 * 2);       // delta_raw bf16 (padded K=64)
    float* delta = (float*)alloc((size_t)Lq * DIN * 4);    // softplus(...)
    float* chA   = (float*)alloc((size_t)NCH * DIN * NST * 4);
    float* chX   = (float*)alloc((size_t)NCH * DIN * NST * 4);
    float* initS = (float*)alloc((size_t)NCH * DIN * NST * 4);
    u16*   ybf   = (u16*)alloc((size_t)Lq * DIN * 2);
    (void)ws_size; (void)in_sizes; (void)n_in; (void)out_size;

    // weight prep (transpose + bf16 cast, zero-padded)
    transpose_cast<<<dim3(96, 24), 256, 0, stream>>>(W_in, 768, 3072, WinT, 768, 3072);
    transpose_cast<<<dim3(24, 48), 256, 0, stream>>>(W_out, 1536, 768, WoutT, 1536, 768);
    transpose_cast<<<dim3(4, 48), 256, 0, stream>>>(W_x, 1536, 80, WxT, 1536, 128);
    transpose_cast<<<dim3(48, 2), 256, 0, stream>>>(W_dt, 48, 1536, WdtT, 64, 1536);

    // rmsnorm
    rmsnorm_kernel<<<Lq, 256, 0, stream>>>(x, norm_w, xn);

    // GEMM1: xn(2048x768) @ W_in(768x3072) -> xr
    gemm_nt<128, 128, 0><<<dim3(3072 / 128, Lq / 128, 1), 256, 0, stream>>>(
        xn, WinT, xr, nullptr, nullptr, Lq, 3072, 768, 768);

    // depthwise conv + silu
    conv_silu<<<(Lq * DIN) / 256, 256, 0, stream>>>(xr, conv_w, conv_b, u, ubf);

    // GEMM2: u(2048x1536) @ W_x(1536x80->128) -> xdbl, split-K=8 + atomics
    hipMemsetAsync(xdbl, 0, (size_t)Lq * 128 * 4, stream);
    gemm_nt<128, 128, 2><<<dim3(1, Lq / 128, 8), 256, 0, stream>>>(
        ubf, WxT, xdbl, nullptr, nullptr, Lq, 128, 1536, 192);

    // delta GEMM: delta_raw(2048x48->64) @ W_dt(48->64 x 1536) + b_dt, softplus
    cast_draw<<<(Lq * 64) / 256, 256, 0, stream>>>(xdbl, draw);
    gemm_nt<128, 128, 1><<<dim3(1536 / 128, Lq / 128, 1), 256, 0, stream>>>(
        draw, WdtT, delta, nullptr, b_dt, Lq, 1536, 64, 64);

    // selective scan (3-pass chunked) + gate -> y bf16
    scan_p1<<<dim3(NCH, DIN / 16), 256, 0, stream>>>(delta, u, xdbl, A_log, chA, chX);
    scan_p2<<<(DIN * NST) / 256, 256, 0, stream>>>(chA, chX, initS);
    scan_p3<<<dim3(NCH, DIN / 16), 256, 0, stream>>>(delta, u, xdbl, A_log, initS, Dp, xr, ybf);

    // GEMM3: y(2048x1536) @ W_out(1536x768) + x -> out
    gemm_nt<64, 64, 0><<<dim3(Dq / 64, Lq / 64, 1), 256, 0, stream>>>(
        ybf, WoutT, out, x, nullptr, Lq, Dq, 1536, 1536);
}

// Round 2
// 261.204 us; speedup vs baseline: 1.2937x; 1.2937x over previous
//
#include <hip/hip_runtime.h>
#include <hip/hip_bf16.h>

typedef unsigned short u16;
typedef __bf16 bfx8 __attribute__((ext_vector_type(8)));
typedef float fx4 __attribute__((ext_vector_type(4)));

#define DEV __device__ __forceinline__

static constexpr int Lq = 2048, Dq = 768, DIN = 1536, NST = 16;
static constexpr int NCH = 64, LC = 32;   // scan chunks: 64 x 32 = 2048

DEV u16 f2bf(float x) {
    union { float f; unsigned u; } v; v.f = x;
    unsigned r = v.u + 0x7fff + ((v.u >> 16) & 1);
    return (u16)(r >> 16);
}

// ---------------- transpose + cast f32 -> bf16, with zero padding ----------------
__global__ __launch_bounds__(256) void transpose_cast(const float* __restrict__ src, int R, int C,
                                                      u16* __restrict__ dst, int Rp, int Cp) {
    __shared__ float tile[32][33];
    int c0 = blockIdx.x * 32, r0 = blockIdx.y * 32;
    int tx = threadIdx.x & 31, ty = threadIdx.x >> 5;   // 32 x 8
    #pragma unroll
    for (int i = ty; i < 32; i += 8) {
        int r = r0 + i, c = c0 + tx;
        tile[i][tx] = (r < R && c < C) ? src[(size_t)r * C + c] : 0.f;
    }
    __syncthreads();
    #pragma unroll
    for (int i = ty; i < 32; i += 8) {
        int c = c0 + i, r = r0 + tx;
        if (c < Cp && r < Rp) dst[(size_t)c * Rp + r] = f2bf(tile[tx][i]);
    }
}

// ---------------- RMSNorm -> bf16 ----------------
__global__ __launch_bounds__(256) void rmsnorm_kernel(const float* __restrict__ x,
                                                      const float* __restrict__ w,
                                                      u16* __restrict__ xn) {
    int t = blockIdx.x;
    const float* row = x + (size_t)t * Dq;
    float ss = 0.f;
    for (int i = threadIdx.x; i < Dq; i += 256) { float a = row[i]; ss += a * a; }
    #pragma unroll
    for (int o = 32; o > 0; o >>= 1) ss += __shfl_xor(ss, o, 64);
    __shared__ float wsum[4];
    if ((threadIdx.x & 63) == 0) wsum[threadIdx.x >> 6] = ss;
    __syncthreads();
    ss = wsum[0] + wsum[1] + wsum[2] + wsum[3];
    float scale = rsqrtf(ss * (1.f / Dq) + 1e-5f);
    for (int i = threadIdx.x; i < Dq; i += 256)
        xn[(size_t)t * Dq + i] = f2bf(row[i] * scale * w[i]);
}

// ---------------- generic NT bf16 MFMA GEMM ----------------
// A: M x K bf16 row-major. BT: N x K bf16 row-major. C: M x N f32.
// EPI 0: C = acc (+R if R). EPI 1: C = softplus(acc + bias[col]). EPI 2: atomicAdd(C, acc).
template<int BM, int BN, int EPI>
__global__ __launch_bounds__(256) void gemm_nt(const u16* __restrict__ A, const u16* __restrict__ BT,
                                               float* __restrict__ C, const float* __restrict__ R,
                                               const float* __restrict__ bias,
                                               int M, int N, int K, int kLen) {
    constexpr int BK = 32, LDT = 40;       // +8 bf16 pad
    constexpr int WM = BM / 2, WN = BN / 2, MI = WM / 16, NI = WN / 16;
    __shared__ u16 As[BM * LDT];
    __shared__ u16 Bs[BN * LDT];
    const int tid = threadIdx.x, lane = tid & 63, wid = tid >> 6;
    const int wr = wid >> 1, wc = wid & 1;
    const int bm0 = blockIdx.y * BM, bn0 = blockIdx.x * BN;
    const int k0 = blockIdx.z * kLen;
    const int li = lane & 15, g = lane >> 4;

    fx4 acc[MI][NI];
    #pragma unroll
    for (int mi = 0; mi < MI; mi++)
        #pragma unroll
        for (int ni = 0; ni < NI; ni++)
            #pragma unroll
            for (int q = 0; q < 4; q++) acc[mi][ni][q] = 0.f;

    for (int kt = k0; kt < k0 + kLen; kt += BK) {
        #pragma unroll
        for (int i = 0; i < (BM * 4) / 256; i++) {
            int ch = tid + i * 256; int r = ch >> 2, kc = (ch & 3) * 8;
            *(float4*)(&As[r * LDT + kc]) = *(const float4*)(A + (size_t)(bm0 + r) * K + kt + kc);
        }
        #pragma unroll
        for (int i = 0; i < (BN * 4) / 256; i++) {
            int ch = tid + i * 256; int r = ch >> 2, kc = (ch & 3) * 8;
            *(float4*)(&Bs[r * LDT + kc]) = *(const float4*)(BT + (size_t)(bn0 + r) * K + kt + kc);
        }
        __syncthreads();
        bfx8 af[MI], bfr[NI];
        #pragma unroll
        for (int mi = 0; mi < MI; mi++) af[mi] = *(const bfx8*)&As[(wr * WM + mi * 16 + li) * LDT + g * 8];
        #pragma unroll
        for (int ni = 0; ni < NI; ni++) bfr[ni] = *(const bfx8*)&Bs[(wc * WN + ni * 16 + li) * LDT + g * 8];
        #pragma unroll
        for (int mi = 0; mi < MI; mi++)
            #pragma unroll
            for (int ni = 0; ni < NI; ni++)
                acc[mi][ni] = __builtin_amdgcn_mfma_f32_16x16x32_bf16(af[mi], bfr[ni], acc[mi][ni], 0, 0, 0);
        __syncthreads();
    }

    #pragma unroll
    for (int mi = 0; mi < MI; mi++)
        #pragma unroll
        for (int ni = 0; ni < NI; ni++)
            #pragma unroll
            for (int q = 0; q < 4; q++) {
                int row = bm0 + wr * WM + mi * 16 + g * 4 + q;
                int col = bn0 + wc * WN + ni * 16 + li;
                size_t idx = (size_t)row * N + col;
                float v = acc[mi][ni][q];
                if constexpr (EPI == 0) {
                    if (R) v += R[idx];
                    C[idx] = v;
                } else if constexpr (EPI == 1) {
                    v += bias[col];
                    C[idx] = (v > 20.f) ? v : log1pf(__expf(v));
                } else {
                    atomicAdd(&C[idx], v);
                }
            }
}

// ---------------- depthwise causal conv (K=4) + bias + SiLU ----------------
__global__ __launch_bounds__(256) void conv_silu(const float* __restrict__ xr,
                                                 const float* __restrict__ cw,
                                                 const float* __restrict__ cb,
                                                 float* __restrict__ u, u16* __restrict__ ubf) {
    int i = blockIdx.x * 256 + threadIdx.x;
    if (i >= Lq * DIN) return;
    int t = i / DIN, d = i - t * DIN;
    float acc = cb[d];
    #pragma unroll
    for (int k = 0; k < 4; k++) {
        int tt = t - 3 + k;
        if (tt >= 0) acc += xr[(size_t)tt * (2 * DIN) + d] * cw[k * DIN + d];
    }
    float s = acc / (1.f + __expf(-acc));
    u[i] = s;
    ubf[i] = f2bf(s);
}

// ---------------- cast delta_raw (cols 0..63 of padded x_dbl) to bf16 ----------------
__global__ __launch_bounds__(256) void cast_draw(const float* __restrict__ xdbl, u16* __restrict__ draw) {
    int i = blockIdx.x * 256 + threadIdx.x;
    if (i >= Lq * 64) return;
    int t = i >> 6, k = i & 63;
    draw[i] = f2bf(xdbl[(size_t)t * 128 + k]);
}

// ---------------- selective scan, 3-pass chunked; thread owns d (16 states in regs) ------
// pass 1: per (chunk, d): local scan from 0; store end-state and analytic chunk A-product.
__global__ __launch_bounds__(256) void scan_p1(const float* __restrict__ delta, const float* __restrict__ u,
                                               const float* __restrict__ xdbl, const float* __restrict__ A_log,
                                               float* __restrict__ chA, float* __restrict__ chX) {
    int c = blockIdx.x;
    int d = blockIdx.y * 256 + threadIdx.x;
    float An[NST];
    #pragma unroll
    for (int i = 0; i < 4; i++) {
        float4 a = *(const float4*)(A_log + (size_t)d * NST + i * 4);
        An[i * 4 + 0] = -__expf(a.x); An[i * 4 + 1] = -__expf(a.y);
        An[i * 4 + 2] = -__expf(a.z); An[i * 4 + 3] = -__expf(a.w);
    }
    float s[NST];
    #pragma unroll
    for (int n = 0; n < NST; n++) s[n] = 0.f;
    float sdl = 0.f;
    int t0 = c * LC;
    for (int t = t0; t < t0 + LC; t++) {
        float dl = delta[(size_t)t * DIN + d];
        float uu = u[(size_t)t * DIN + d];
        float dlu = dl * uu;
        float Bv[NST];
        #pragma unroll
        for (int i = 0; i < 4; i++) {
            float4 b = *(const float4*)(xdbl + (size_t)t * 128 + 48 + i * 4);
            Bv[i * 4 + 0] = b.x; Bv[i * 4 + 1] = b.y; Bv[i * 4 + 2] = b.z; Bv[i * 4 + 3] = b.w;
        }
        #pragma unroll
        for (int n = 0; n < NST; n++) {
            float dA = __expf(dl * An[n]);
            s[n] = fmaf(dA, s[n], dlu * Bv[n]);
        }
        sdl += dl;
    }
    size_t base = ((size_t)c * DIN + d) * NST;
    #pragma unroll
    for (int i = 0; i < 4; i++) {
        float4 v; v.x = s[i*4]; v.y = s[i*4+1]; v.z = s[i*4+2]; v.w = s[i*4+3];
        *(float4*)(chX + base + i * 4) = v;
    }
    #pragma unroll
    for (int i = 0; i < 4; i++) {
        float4 v;
        v.x = __expf(An[i*4+0] * sdl); v.y = __expf(An[i*4+1] * sdl);
        v.z = __expf(An[i*4+2] * sdl); v.w = __expf(An[i*4+3] * sdl);
        *(float4*)(chA + base + i * 4) = v;
    }
}

// pass 2: sequential combine over chunks; writes the chunk-initial state IN PLACE into chA.
__global__ __launch_bounds__(256) void scan_p2(float* __restrict__ chA, const float* __restrict__ chX) {
    int i = blockIdx.x * 256 + threadIdx.x;   // i = d*16+n
    float s = 0.f;
    for (int c = 0; c < NCH; c++) {
        size_t idx = (size_t)c * (DIN * NST) + i;
        float a = chA[idx], xv = chX[idx];
        chA[idx] = s;               // becomes init-state for chunk c
        s = fmaf(a, s, xv);
    }
}

// pass 3: rescan with init (in chA), in-register n-reduction, gate, -> y bf16.
__global__ __launch_bounds__(256) void scan_p3(const float* __restrict__ delta, const float* __restrict__ u,
                                               const float* __restrict__ xdbl, const float* __restrict__ A_log,
                                               const float* __restrict__ init, const float* __restrict__ Dp,
                                               const float* __restrict__ xr, u16* __restrict__ ybf) {
    int c = blockIdx.x;
    int d = blockIdx.y * 256 + threadIdx.x;
    float An[NST];
    #pragma unroll
    for (int i = 0; i < 4; i++) {
        float4 a = *(const float4*)(A_log + (size_t)d * NST + i * 4);
        An[i * 4 + 0] = -__expf(a.x); An[i * 4 + 1] = -__expf(a.y);
        An[i * 4 + 2] = -__expf(a.z); An[i * 4 + 3] = -__expf(a.w);
    }
    float s[NST];
    size_t base = ((size_t)c * DIN + d) * NST;
    #pragma unroll
    for (int i = 0; i < 4; i++) {
        float4 v = *(const float4*)(init + base + i * 4);
        s[i * 4 + 0] = v.x; s[i * 4 + 1] = v.y; s[i * 4 + 2] = v.z; s[i * 4 + 3] = v.w;
    }
    float Dpd = Dp[d];
    int t0 = c * LC;
    for (int t = t0; t < t0 + LC; t++) {
        float dl = delta[(size_t)t * DIN + d];
        float uu = u[(size_t)t * DIN + d];
        float dlu = dl * uu;
        float Bv[NST], Cv[NST];
        #pragma unroll
        for (int i = 0; i < 4; i++) {
            float4 b = *(const float4*)(xdbl + (size_t)t * 128 + 48 + i * 4);
            Bv[i * 4 + 0] = b.x; Bv[i * 4 + 1] = b.y; Bv[i * 4 + 2] = b.z; Bv[i * 4 + 3] = b.w;
            float4 cc = *(const float4*)(xdbl + (size_t)t * 128 + 64 + i * 4);
            Cv[i * 4 + 0] = cc.x; Cv[i * 4 + 1] = cc.y; Cv[i * 4 + 2] = cc.z; Cv[i * 4 + 3] = cc.w;
        }
        float p = 0.f;
        #pragma unroll
        for (int n = 0; n < NST; n++) {
            float dA = __expf(dl * An[n]);
            s[n] = fmaf(dA, s[n], dlu * Bv[n]);
            p = fmaf(s[n], Cv[n], p);
        }
        float res = xr[(size_t)t * (2 * DIN) + DIN + d];
        float y = fmaf(uu, Dpd, p) * (res / (1.f + __expf(-res)));
        ybf[(size_t)t * DIN + d] = f2bf(y);
    }
}

extern "C" void kernel_launch(void* const* d_in, const int* in_sizes, int n_in,
                              void* d_out, int out_size, void* d_ws, size_t ws_size,
                              hipStream_t stream) {
    const float* x      = (const float*)d_in[0];
    const float* norm_w = (const float*)d_in[1];
    const float* W_in   = (const float*)d_in[2];
    const float* conv_w = (const float*)d_in[3];
    const float* conv_b = (const float*)d_in[4];
    const float* W_x    = (const float*)d_in[5];
    const float* W_dt   = (const float*)d_in[6];
    const float* b_dt   = (const float*)d_in[7];
    const float* A_log  = (const float*)d_in[8];
    const float* Dp     = (const float*)d_in[9];
    const float* W_out  = (const float*)d_in[10];
    float* out = (float*)d_out;

    char* wp = (char*)d_ws;
    auto alloc = [&](size_t bytes) { char* p = wp; wp += (bytes + 255) & ~(size_t)255; return p; };
    // --- overlap region: phase-A buffers (dead before scan) reused as chA/chX ---
    char*  region = alloc(15007744);                        // 15.0 MB
    u16*   WinT = (u16*)(region);                           // 4,718,592 B
    u16*   xn   = (u16*)(region + 4718592);                 // 3,145,728 B
    u16*   ubf  = (u16*)(region + 7864320);                 // 6,291,456 B
    u16*   draw = (u16*)(region + 14155776);                //   262,144 B
    u16*   WxT  = (u16*)(region + 14417920);                //   393,216 B
    u16*   WdtT = (u16*)(region + 14811136);                //   196,608 B
    float* chA  = (float*)(region);                         // 6,291,456 B (scan phase)
    float* chX  = (float*)(region + 6291456);               // 6,291,456 B (scan phase)
    // --- persistent buffers ---
    u16*   WoutT = (u16*)alloc((size_t)768 * 1536 * 2);
    float* xr    = (float*)alloc((size_t)Lq * 3072 * 4);
    float* u     = (float*)alloc((size_t)Lq * DIN * 4);
    float* xdbl  = (float*)alloc((size_t)Lq * 128 * 4);
    float* delta = (float*)alloc((size_t)Lq * DIN * 4);
    u16*   ybf   = (u16*)alloc((size_t)Lq * DIN * 2);
    (void)ws_size; (void)in_sizes; (void)n_in; (void)out_size;

    // weight prep (transpose + bf16 cast, zero-padded)
    transpose_cast<<<dim3(96, 24), 256, 0, stream>>>(W_in, 768, 3072, WinT, 768, 3072);
    transpose_cast<<<dim3(24, 48), 256, 0, stream>>>(W_out, 1536, 768, WoutT, 1536, 768);
    transpose_cast<<<dim3(4, 48), 256, 0, stream>>>(W_x, 1536, 80, WxT, 1536, 128);
    transpose_cast<<<dim3(48, 2), 256, 0, stream>>>(W_dt, 48, 1536, WdtT, 64, 1536);

    // rmsnorm
    rmsnorm_kernel<<<Lq, 256, 0, stream>>>(x, norm_w, xn);

    // GEMM1: xn(2048x768) @ W_in(768x3072) -> xr
    gemm_nt<128, 128, 0><<<dim3(3072 / 128, Lq / 128, 1), 256, 0, stream>>>(
        xn, WinT, xr, nullptr, nullptr, Lq, 3072, 768, 768);

    // depthwise conv + silu
    conv_silu<<<(Lq * DIN) / 256, 256, 0, stream>>>(xr, conv_w, conv_b, u, ubf);

    // GEMM2: u(2048x1536) @ W_x(1536x80->128) -> xdbl, split-K=8 + atomics
    hipMemsetAsync(xdbl, 0, (size_t)Lq * 128 * 4, stream);
    gemm_nt<128, 128, 2><<<dim3(1, Lq / 128, 8), 256, 0, stream>>>(
        ubf, WxT, xdbl, nullptr, nullptr, Lq, 128, 1536, 192);

    // delta GEMM: delta_raw(2048x48->64) @ W_dt(48->64 x 1536) + b_dt, softplus
    cast_draw<<<(Lq * 64) / 256, 256, 0, stream>>>(xdbl, draw);
    gemm_nt<128, 128, 1><<<dim3(1536 / 128, Lq / 128, 1), 256, 0, stream>>>(
        draw, WdtT, delta, nullptr, b_dt, Lq, 1536, 64, 64);

    // selective scan (3-pass chunked, 16 states per thread) + gate -> y bf16
    scan_p1<<<dim3(NCH, DIN / 256), 256, 0, stream>>>(delta, u, xdbl, A_log, chA, chX);
    scan_p2<<<(DIN * NST) / 256, 256, 0, stream>>>(chA, chX);
    scan_p3<<<dim3(NCH, DIN / 256), 256, 0, stream>>>(delta, u, xdbl, A_log, chA, Dp, xr, ybf);

    // GEMM3: y(2048x1536) @ W_out(1536x768) + x -> out
    gemm_nt<64, 64, 0><<<dim3(Dq / 64, Lq / 64, 1), 256, 0, stream>>>(
        ybf, WoutT, out, x, nullptr, Lq, Dq, 1536, 1536);
}

// Round 3
// 244.906 us; speedup vs baseline: 1.3798x; 1.0665x over previous
//
#include <hip/hip_runtime.h>
#include <hip/hip_bf16.h>

typedef unsigned short u16;
typedef __bf16 bfx8 __attribute__((ext_vector_type(8)));
typedef float fx4 __attribute__((ext_vector_type(4)));
typedef unsigned short ushort8 __attribute__((ext_vector_type(8)));

#define DEV __device__ __forceinline__

static constexpr int Lq = 2048, Dq = 768, DIN = 1536, NST = 16;
static constexpr int NCH = 64, LC = 32;   // scan chunks: 64 x 32 = 2048

DEV u16 f2bf(float x) {
    union { float f; unsigned u; } v; v.f = x;
    unsigned r = v.u + 0x7fff + ((v.u >> 16) & 1);
    return (u16)(r >> 16);
}
DEV float bf2f(u16 v) {
    union { unsigned u; float f; } w; w.u = ((unsigned)v) << 16; return w.f;
}
// async 16B global->LDS (wave-uniform LDS base + lane*16, per-lane global addr)
DEV void gll16(const u16* g, u16* l) {
    __builtin_amdgcn_global_load_lds(
        (const __attribute__((address_space(1))) unsigned int*)g,
        (__attribute__((address_space(3))) unsigned int*)l, 16, 0, 0);
}

// ---------------- batched transpose + cast f32 -> bf16, zero padding ----------------
struct TD { const float* src; u16* dst; int R, C, Rp, Cp, nbx, blk0; };

__global__ __launch_bounds__(256) void transpose_all(TD t0, TD t1, TD t2, TD t3) {
    __shared__ float tile[32][33];
    TD td = t0;
    int b = blockIdx.x;
    if (b >= t3.blk0) td = t3; else if (b >= t2.blk0) td = t2; else if (b >= t1.blk0) td = t1;
    int local = b - td.blk0;
    int c0 = (local % td.nbx) * 32, r0 = (local / td.nbx) * 32;
    int tx = threadIdx.x & 31, ty = threadIdx.x >> 5;   // 32 x 8
    #pragma unroll
    for (int i = ty; i < 32; i += 8) {
        int r = r0 + i, c = c0 + tx;
        tile[i][tx] = (r < td.R && c < td.C) ? td.src[(size_t)r * td.C + c] : 0.f;
    }
    __syncthreads();
    #pragma unroll
    for (int i = ty; i < 32; i += 8) {
        int c = c0 + i, r = r0 + tx;
        if (c < td.Cp && r < td.Rp) td.dst[(size_t)c * td.Rp + r] = f2bf(tile[tx][i]);
    }
}

// ---------------- RMSNorm -> bf16 ----------------
__global__ __launch_bounds__(256) void rmsnorm_kernel(const float* __restrict__ x,
                                                      const float* __restrict__ w,
                                                      u16* __restrict__ xn) {
    int t = blockIdx.x;
    const float* row = x + (size_t)t * Dq;
    float ss = 0.f;
    for (int i = threadIdx.x; i < Dq; i += 256) { float a = row[i]; ss += a * a; }
    #pragma unroll
    for (int o = 32; o > 0; o >>= 1) ss += __shfl_xor(ss, o, 64);
    __shared__ float wsum[4];
    if ((threadIdx.x & 63) == 0) wsum[threadIdx.x >> 6] = ss;
    __syncthreads();
    ss = wsum[0] + wsum[1] + wsum[2] + wsum[3];
    float scale = rsqrtf(ss * (1.f / Dq) + 1e-5f);
    for (int i = threadIdx.x; i < Dq; i += 256)
        xn[(size_t)t * Dq + i] = f2bf(row[i] * scale * w[i]);
}

// ---------------- generic NT bf16 MFMA GEMM, global_load_lds staging ----------------
// A: M x K bf16 row-major. BT: N x K bf16 row-major.
// EPI 0: C=acc(+R). EPI 3: Cb=bf16(acc). EPI 4: Cb=bf16(softplus(acc+bias[col])).
// EPI 5: C=acc (f32) AND if col<64 Cb[row*64+col]=bf16(acc).
template<int BM, int BN, int EPI>
__global__ __launch_bounds__(256) void gemm_nt(const u16* __restrict__ A, const u16* __restrict__ BT,
                                               float* __restrict__ C, u16* __restrict__ Cb,
                                               const float* __restrict__ R,
                                               const float* __restrict__ bias,
                                               int M, int N, int K) {
    constexpr int BK = 32;
    constexpr int WM = BM / 2, WN = BN / 2, MI = WM / 16, NI = WN / 16;
    __shared__ u16 As[BM * BK];
    __shared__ u16 Bs[BN * BK];
    const int tid = threadIdx.x, lane = tid & 63, wid = tid >> 6;
    const int wr = wid >> 1, wc = wid & 1;
    const int bm0 = blockIdx.y * BM, bn0 = blockIdx.x * BN;
    const int li = lane & 15, g = lane >> 4;

    fx4 acc[MI][NI];
    #pragma unroll
    for (int mi = 0; mi < MI; mi++)
        #pragma unroll
        for (int ni = 0; ni < NI; ni++)
            #pragma unroll
            for (int q = 0; q < 4; q++) acc[mi][ni][q] = 0.f;

    for (int kt = 0; kt < K; kt += BK) {
        // stage A: BM*4 16B-chunks; chunk c -> LDS bytes [c*16, c*16+16) = row c>>2, cols (c&3)*8..
        #pragma unroll
        for (int i = 0; i < BM / 64; i++) {
            int c = (i * 4 + wid) * 64 + lane;
            gll16(A + (size_t)(bm0 + (c >> 2)) * K + kt + (c & 3) * 8, &As[(i * 4 + wid) * 512]);
        }
        #pragma unroll
        for (int i = 0; i < BN / 64; i++) {
            int c = (i * 4 + wid) * 64 + lane;
            gll16(BT + (size_t)(bn0 + (c >> 2)) * K + kt + (c & 3) * 8, &Bs[(i * 4 + wid) * 512]);
        }
        __syncthreads();
        bfx8 af[MI], bfr[NI];
        #pragma unroll
        for (int mi = 0; mi < MI; mi++) af[mi] = *(const bfx8*)&As[(wr * WM + mi * 16 + li) * BK + g * 8];
        #pragma unroll
        for (int ni = 0; ni < NI; ni++) bfr[ni] = *(const bfx8*)&Bs[(wc * WN + ni * 16 + li) * BK + g * 8];
        #pragma unroll
        for (int mi = 0; mi < MI; mi++)
            #pragma unroll
            for (int ni = 0; ni < NI; ni++)
                acc[mi][ni] = __builtin_amdgcn_mfma_f32_16x16x32_bf16(af[mi], bfr[ni], acc[mi][ni], 0, 0, 0);
        __syncthreads();
    }

    #pragma unroll
    for (int mi = 0; mi < MI; mi++)
        #pragma unroll
        for (int ni = 0; ni < NI; ni++)
            #pragma unroll
            for (int q = 0; q < 4; q++) {
                int row = bm0 + wr * WM + mi * 16 + g * 4 + q;
                int col = bn0 + wc * WN + ni * 16 + li;
                size_t idx = (size_t)row * N + col;
                float v = acc[mi][ni][q];
                if constexpr (EPI == 0) {
                    if (R) v += R[idx];
                    C[idx] = v;
                } else if constexpr (EPI == 3) {
                    Cb[idx] = f2bf(v);
                } else if constexpr (EPI == 4) {
                    v += bias[col];
                    Cb[idx] = f2bf((v > 20.f) ? v : log1pf(__expf(v)));
                } else if constexpr (EPI == 5) {
                    C[idx] = v;
                    if (col < 64) Cb[(size_t)row * 64 + col] = f2bf(v);
                }
            }
}

// ---------------- depthwise causal conv (K=4) + bias + SiLU, 8-wide bf16 ----------------
__global__ __launch_bounds__(256) void conv_silu(const u16* __restrict__ xrb,
                                                 const float* __restrict__ cw,
                                                 const float* __restrict__ cb,
                                                 u16* __restrict__ ubf) {
    int i = blockIdx.x * 256 + threadIdx.x;            // one 8-group
    int t = i / (DIN / 8), d8 = (i - t * (DIN / 8)) * 8;
    float acc[8];
    #pragma unroll
    for (int j = 0; j < 8; j++) acc[j] = cb[d8 + j];
    #pragma unroll
    for (int k = 0; k < 4; k++) {
        int tt = t - 3 + k;
        if (tt < 0) continue;
        ushort8 xv = *(const ushort8*)(xrb + (size_t)tt * (2 * DIN) + d8);
        #pragma unroll
        for (int j = 0; j < 8; j++) acc[j] = fmaf(bf2f(xv[j]), cw[k * DIN + d8 + j], acc[j]);
    }
    ushort8 o;
    #pragma unroll
    for (int j = 0; j < 8; j++) {
        float s = acc[j] / (1.f + __expf(-acc[j]));
        o[j] = f2bf(s);
    }
    *(ushort8*)(ubf + (size_t)i * 8) = o;
}

// ---------------- selective scan, 3-pass chunked; thread owns d (16 states in regs) ------
__global__ __launch_bounds__(256) void scan_p1(const u16* __restrict__ deltab, const u16* __restrict__ ubf,
                                               const float* __restrict__ xdbl, const float* __restrict__ A_log,
                                               float* __restrict__ chA, float* __restrict__ chX) {
    int c = blockIdx.x;
    int d = blockIdx.y * 256 + threadIdx.x;
    float An[NST];
    #pragma unroll
    for (int i = 0; i < 4; i++) {
        float4 a = *(const float4*)(A_log + (size_t)d * NST + i * 4);
        An[i * 4 + 0] = -__expf(a.x); An[i * 4 + 1] = -__expf(a.y);
        An[i * 4 + 2] = -__expf(a.z); An[i * 4 + 3] = -__expf(a.w);
    }
    float s[NST];
    #pragma unroll
    for (int n = 0; n < NST; n++) s[n] = 0.f;
    float sdl = 0.f;
    int t0 = c * LC;
    for (int t = t0; t < t0 + LC; t++) {
        float dl = bf2f(deltab[(size_t)t * DIN + d]);
        float uu = bf2f(ubf[(size_t)t * DIN + d]);
        float dlu = dl * uu;
        float Bv[NST];
        #pragma unroll
        for (int i = 0; i < 4; i++) {
            float4 b = *(const float4*)(xdbl + (size_t)t * 128 + 48 + i * 4);
            Bv[i * 4 + 0] = b.x; Bv[i * 4 + 1] = b.y; Bv[i * 4 + 2] = b.z; Bv[i * 4 + 3] = b.w;
        }
        #pragma unroll
        for (int n = 0; n < NST; n++) {
            float dA = __expf(dl * An[n]);
            s[n] = fmaf(dA, s[n], dlu * Bv[n]);
        }
        sdl += dl;
    }
    size_t base = ((size_t)c * DIN + d) * NST;
    #pragma unroll
    for (int i = 0; i < 4; i++) {
        float4 v; v.x = s[i*4]; v.y = s[i*4+1]; v.z = s[i*4+2]; v.w = s[i*4+3];
        *(float4*)(chX + base + i * 4) = v;
    }
    #pragma unroll
    for (int i = 0; i < 4; i++) {
        float4 v;
        v.x = __expf(An[i*4+0] * sdl); v.y = __expf(An[i*4+1] * sdl);
        v.z = __expf(An[i*4+2] * sdl); v.w = __expf(An[i*4+3] * sdl);
        *(float4*)(chA + base + i * 4) = v;
    }
}

__global__ __launch_bounds__(256) void scan_p2(float* __restrict__ chA, const float* __restrict__ chX) {
    int i = blockIdx.x * 256 + threadIdx.x;   // i = d*16+n
    float s = 0.f;
    for (int c = 0; c < NCH; c++) {
        size_t idx = (size_t)c * (DIN * NST) + i;
        float a = chA[idx], xv = chX[idx];
        chA[idx] = s;               // becomes init-state for chunk c
        s = fmaf(a, s, xv);
    }
}

__global__ __launch_bounds__(256) void scan_p3(const u16* __restrict__ deltab, const u16* __restrict__ ubf,
                                               const float* __restrict__ xdbl, const float* __restrict__ A_log,
                                               const float* __restrict__ init, const float* __restrict__ Dp,
                                               const u16* __restrict__ xrb, u16* __restrict__ ybf) {
    int c = blockIdx.x;
    int d = blockIdx.y * 256 + threadIdx.x;
    float An[NST];
    #pragma unroll
    for (int i = 0; i < 4; i++) {
        float4 a = *(const float4*)(A_log + (size_t)d * NST + i * 4);
        An[i * 4 + 0] = -__expf(a.x); An[i * 4 + 1] = -__expf(a.y);
        An[i * 4 + 2] = -__expf(a.z); An[i * 4 + 3] = -__expf(a.w);
    }
    float s[NST];
    size_t base = ((size_t)c * DIN + d) * NST;
    #pragma unroll
    for (int i = 0; i < 4; i++) {
        float4 v = *(const float4*)(init + base + i * 4);
        s[i * 4 + 0] = v.x; s[i * 4 + 1] = v.y; s[i * 4 + 2] = v.z; s[i * 4 + 3] = v.w;
    }
    float Dpd = Dp[d];
    int t0 = c * LC;
    for (int t = t0; t < t0 + LC; t++) {
        float dl = bf2f(deltab[(size_t)t * DIN + d]);
        float uu = bf2f(ubf[(size_t)t * DIN + d]);
        float dlu = dl * uu;
        float Bv[NST], Cv[NST];
        #pragma unroll
        for (int i = 0; i < 4; i++) {
            float4 b = *(const float4*)(xdbl + (size_t)t * 128 + 48 + i * 4);
            Bv[i * 4 + 0] = b.x; Bv[i * 4 + 1] = b.y; Bv[i * 4 + 2] = b.z; Bv[i * 4 + 3] = b.w;
            float4 cc = *(const float4*)(xdbl + (size_t)t * 128 + 64 + i * 4);
            Cv[i * 4 + 0] = cc.x; Cv[i * 4 + 1] = cc.y; Cv[i * 4 + 2] = cc.z; Cv[i * 4 + 3] = cc.w;
        }
        float p = 0.f;
        #pragma unroll
        for (int n = 0; n < NST; n++) {
            float dA = __expf(dl * An[n]);
            s[n] = fmaf(dA, s[n], dlu * Bv[n]);
            p = fmaf(s[n], Cv[n], p);
        }
        float res = bf2f(xrb[(size_t)t * (2 * DIN) + DIN + d]);
        float y = fmaf(uu, Dpd, p) * (res / (1.f + __expf(-res)));
        ybf[(size_t)t * DIN + d] = f2bf(y);
    }
}

extern "C" void kernel_launch(void* const* d_in, const int* in_sizes, int n_in,
                              void* d_out, int out_size, void* d_ws, size_t ws_size,
                              hipStream_t stream) {
    const float* x      = (const float*)d_in[0];
    const float* norm_w = (const float*)d_in[1];
    const float* W_in   = (const float*)d_in[2];
    const float* conv_w = (const float*)d_in[3];
    const float* conv_b = (const float*)d_in[4];
    const float* W_x    = (const float*)d_in[5];
    const float* W_dt   = (const float*)d_in[6];
    const float* b_dt   = (const float*)d_in[7];
    const float* A_log  = (const float*)d_in[8];
    const float* Dp     = (const float*)d_in[9];
    const float* W_out  = (const float*)d_in[10];
    float* out = (float*)d_out;

    char* wp = (char*)d_ws;
    auto alloc = [&](size_t bytes) { char* p = wp; wp += (bytes + 255) & ~(size_t)255; return p; };
    u16*   WinT   = (u16*)alloc((size_t)3072 * 768 * 2);
    u16*   WoutT  = (u16*)alloc((size_t)768 * 1536 * 2);
    u16*   WxT    = (u16*)alloc((size_t)128 * 1536 * 2);
    u16*   WdtT   = (u16*)alloc((size_t)1536 * 64 * 2);
    u16*   xn     = (u16*)alloc((size_t)Lq * Dq * 2);
    u16*   xrb    = (u16*)alloc((size_t)Lq * 3072 * 2);   // bf16 x@W_in (xs | res)
    u16*   ubf    = (u16*)alloc((size_t)Lq * DIN * 2);
    float* xdbl   = (float*)alloc((size_t)Lq * 128 * 4);
    u16*   draw   = (u16*)alloc((size_t)Lq * 64 * 2);
    u16*   deltab = (u16*)alloc((size_t)Lq * DIN * 2);
    float* chA    = (float*)alloc((size_t)NCH * DIN * NST * 4);
    float* chX    = (float*)alloc((size_t)NCH * DIN * NST * 4);
    u16*   ybf    = (u16*)alloc((size_t)Lq * DIN * 2);
    (void)ws_size; (void)in_sizes; (void)n_in; (void)out_size;

    // batched weight prep (transpose + bf16 cast, zero-padded): 4 segments, 1 launch
    TD t0{W_in,  WinT,  768, 3072,  768, 3072, 96,    0};   // 96x24 = 2304 blocks
    TD t1{W_out, WoutT, 1536, 768, 1536,  768, 24, 2304};   // 24x48 = 1152
    TD t2{W_x,   WxT,  1536,   80, 1536,  128,  4, 3456};   // 4x48  = 192
    TD t3{W_dt,  WdtT,   48, 1536,   64, 1536, 48, 3648};   // 48x2  = 96 -> total 3744
    transpose_all<<<3744, 256, 0, stream>>>(t0, t1, t2, t3);

    rmsnorm_kernel<<<Lq, 256, 0, stream>>>(x, norm_w, xn);

    // GEMM1: xn(2048x768) @ W_in(768x3072) -> xrb (bf16)
    gemm_nt<128, 128, 3><<<dim3(3072 / 128, Lq / 128), 256, 0, stream>>>(
        xn, WinT, nullptr, xrb, nullptr, nullptr, Lq, 3072, 768);

    // depthwise conv + silu -> ubf (bf16)
    conv_silu<<<(Lq * DIN / 8) / 256, 256, 0, stream>>>(xrb, conv_w, conv_b, ubf);

    // GEMM2: u(2048x1536) @ W_x(1536x80->128) -> xdbl f32 + draw bf16 (cols<64)
    gemm_nt<64, 64, 5><<<dim3(128 / 64, Lq / 64), 256, 0, stream>>>(
        ubf, WxT, xdbl, draw, nullptr, nullptr, Lq, 128, DIN);

    // delta GEMM: draw(2048x64) @ W_dt^T(1536x64) + b_dt -> softplus -> deltab (bf16)
    gemm_nt<128, 128, 4><<<dim3(1536 / 128, Lq / 128), 256, 0, stream>>>(
        draw, WdtT, nullptr, deltab, nullptr, b_dt, Lq, DIN, 64);

    // selective scan (3-pass chunked, 16 states per thread) + gate -> ybf
    scan_p1<<<dim3(NCH, DIN / 256), 256, 0, stream>>>(deltab, ubf, xdbl, A_log, chA, chX);
    scan_p2<<<(DIN * NST) / 256, 256, 0, stream>>>(chA, chX);
    scan_p3<<<dim3(NCH, DIN / 256), 256, 0, stream>>>(deltab, ubf, xdbl, A_log, chA, Dp, xrb, ybf);

    // GEMM3: y(2048x1536) @ W_out(1536x768) + x -> out (f32)
    gemm_nt<64, 64, 0><<<dim3(Dq / 64, Lq / 64), 256, 0, stream>>>(
        ybf, WoutT, out, nullptr, x, nullptr, Lq, Dq, DIN);
}